// Round 5
// baseline (781.993 us; speedup 1.0000x reference)
//
#include <hip/hip_runtime.h>

typedef _Float16 half8 __attribute__((ext_vector_type(8)));
typedef float f32x16 __attribute__((ext_vector_type(16)));

#define M_TRAIN 50000
#define NQ 4096
#define KNN 31

#define LO_SCALE 1024.0f
#define LO_INV   9.765625e-4f

// ---------------------------------------------------------------------------
// Weight prep: fp32 -> fp16 hi/lo (lo scaled x1024), B-fragment-major for
// mfma_f32_32x32x16_f16. Wp[ks][nt][lane][j] <- W[ks*16+(lane>>5)*8+j][nt*32+(lane&31)]
// W0: K padded to 272 (rows 256=y, 257=ind, 258..271 = 0). W1/W2: K=256.
// ---------------------------------------------------------------------------
__global__ void prep_weights_k(const float* __restrict__ W0,
                               const float* __restrict__ W1,
                               const float* __restrict__ W2,
                               _Float16* __restrict__ W0hi, _Float16* __restrict__ W0lo,
                               _Float16* __restrict__ W1hi, _Float16* __restrict__ W1lo,
                               _Float16* __restrict__ W2hi, _Float16* __restrict__ W2lo) {
    int t = blockIdx.x * 256 + threadIdx.x;
    const int n0 = 17 * 8 * 64, n1 = 16 * 8 * 64, n2 = 16 * 8 * 64;
    if (t >= n0 + n1 + n2) return;
    const float* src; _Float16 *dhi, *dlo; int idx, Kin;
    if (t < n0)           { src = W0; dhi = W0hi; dlo = W0lo; idx = t;           Kin = 258; }
    else if (t < n0 + n1) { src = W1; dhi = W1hi; dlo = W1lo; idx = t - n0;      Kin = 256; }
    else                  { src = W2; dhi = W2hi; dlo = W2lo; idx = t - n0 - n1; Kin = 256; }
    int lane = idx & 63, nt = (idx >> 6) & 7, ks = idx >> 9;
    int col = nt * 32 + (lane & 31);
    int k0  = ks * 16 + (lane >> 5) * 8;
    _Float16 vhi[8], vlo[8];
#pragma unroll
    for (int j = 0; j < 8; j++) {
        int k = k0 + j;
        float w = (k < Kin) ? src[k * 256 + col] : 0.f;
        _Float16 hi = (_Float16)w;
        vhi[j] = hi;
        vlo[j] = (_Float16)((w - (float)hi) * LO_SCALE);
    }
    *reinterpret_cast<uint4*>(dhi + (size_t)idx * 8) = *reinterpret_cast<const uint4*>(vhi);
    *reinterpret_cast<uint4*>(dlo + (size_t)idx * 8) = *reinterpret_cast<const uint4*>(vlo);
}

// ---------------------------------------------------------------------------
// kNN: top-31 under EXACT float64 ordering (ref = numpy float64 recompute),
// ties -> lower index (stable top_k). 11-bit float-bin histogram (exp + 3
// mantissa bits) of f32 direct-form d2 bounds the 31st distance to within
// 12.5% -> tight collection threshold, worst-case candidates ~60 (no
// overflow). Exact f64 rank among candidates.
// ---------------------------------------------------------------------------
#define QPB 16
#define TILE 2048
#define NBINS2 2048
#define CAP 160

__global__ __launch_bounds__(256) void knn_k(const float* __restrict__ qs,
                                             const float* __restrict__ ts,
                                             int* __restrict__ nb) {
    __shared__ __align__(16) char S[16384 + 65536];
    float*          tile = (float*)S;                      // [4096] staging
    unsigned short* hist = (unsigned short*)(S + 16384);   // [QPB][2048] u16
    int*            ci   = (int*)(S + 16384);              // [QPB][CAP] (after walk)
    double*         chd  = (double*)(S + 32768);           // [QPB][CAP] f64 keys
    __shared__ int   cnt[QPB];
    __shared__ float thr[QPB];

    const int t = threadIdx.x;
    const int q0 = blockIdx.x * QPB;
    const int wave = t >> 6, lane = t & 63;
    const int qi = wave * 4 + (lane >> 4);
    const int pl = lane & 15;

    for (int i = t; i < QPB * NBINS2 / 2; i += 256) ((unsigned*)hist)[i] = 0u;
    if (t < QPB) cnt[t] = 0;
    const float qx = qs[(q0 + qi) * 2 + 0], qy = qs[(q0 + qi) * 2 + 1];
    __syncthreads();

    // pass 1: 11-bit float-bin histogram of direct-form f32 d2 (u16 counts,
    // updated as packed halves of u32 words; totals <= 50000 so no carry).
    for (int base = 0; base < M_TRAIN; base += TILE) {
        const int n = min(TILE, M_TRAIN - base);
        for (int i = t; i < n * 2; i += 256) tile[i] = ts[base * 2 + i];
        __syncthreads();
        unsigned* h32 = (unsigned*)(hist + qi * NBINS2);
        for (int p = pl; p < n; p += 16) {
            float dx = qx - tile[p * 2], dy = qy - tile[p * 2 + 1];
            float d2 = dx * dx + dy * dy;
            unsigned bin = __float_as_uint(d2) >> 20;      // exp + 3 mantissa bits
            atomicAdd(&h32[bin >> 1], 1u << ((bin & 1) * 16));
        }
        __syncthreads();
    }
    // walk: first bin where cumulative count >= 31 -> tight upper edge
    if (t < QPB) {
        const unsigned* h32 = (const unsigned*)(hist + t * NBINS2);
        unsigned cum = 0; int bfound = 2046;
        for (int wb = 0; wb < NBINS2 / 2; wb++) {
            unsigned v = h32[wb];
            unsigned lo = v & 0xFFFFu, hi = v >> 16;
            if (cum + lo >= 31u)      { bfound = 2 * wb;     break; }
            if (cum + lo + hi >= 31u) { bfound = 2 * wb + 1; break; }
            cum += lo + hi;
        }
        float edge = __uint_as_float((unsigned)(bfound + 1) << 20);
        thr[t] = edge * 1.0005f + 3.2e-5f;   // covers f32-vs-f64 d2 noise
    }
    __syncthreads();
    const float mythr = thr[qi];

    // pass 2: collect candidate indices (hist region dead -> reused as ci)
    for (int base = 0; base < M_TRAIN; base += TILE) {
        const int n = min(TILE, M_TRAIN - base);
        for (int i = t; i < n * 2; i += 256) tile[i] = ts[base * 2 + i];
        __syncthreads();
        for (int p = pl; p < n; p += 16) {
            float dx = qx - tile[p * 2], dy = qy - tile[p * 2 + 1];
            float d2 = dx * dx + dy * dy;
            if (d2 < mythr) {
                int pos = atomicAdd(&cnt[qi], 1);
                if (pos < CAP) ci[qi * CAP + pos] = base + p;
            }
        }
        __syncthreads();
    }

    // pass 3: exact float64 rank among candidates, ties -> lower index
    const int C = min(cnt[qi], CAP);
    for (int c = pl; c < C; c += 16) {
        int idx = ci[qi * CAP + c];
        double dx = (double)qx - (double)ts[idx * 2];
        double dy = (double)qy - (double)ts[idx * 2 + 1];
        chd[qi * CAP + c] = dx * dx + dy * dy;
    }
    __syncthreads();
    for (int c = pl; c < C; c += 16) {
        double key = chd[qi * CAP + c];
        int   idx = ci[qi * CAP + c];
        int rank = 0;
        for (int o = 0; o < C; o++) {
            double ok = chd[qi * CAP + o];
            int    oi = ci[qi * CAP + o];
            rank += ((ok < key) || (ok == key && oi < idx)) ? 1 : 0;
        }
        if (rank < KNN) nb[(q0 + qi) * KNN + rank] = idx;
    }
}

// ---------------------------------------------------------------------------
// Fused graph build + 3-layer GCN + head. 1 graph (32 nodes) per block.
// All fp16 operands carried as (hi, lo*1024); 3-term split MFMA gives
// fp32-accurate products. LDS union: X(hi/lo)[32][276]  <->  T^T(hi/lo)[256][36].
// ---------------------------------------------------------------------------
#define PX 276   // X/H row pitch in fp16
#define PT 36    // T^T / Ahat row pitch in fp16

__device__ inline half8 ld_h8(const _Float16* p) {   // LDS, 8B aligned
    union { half8 h; uint2 u[2]; } r;
    r.u[0] = *reinterpret_cast<const uint2*>(p);
    r.u[1] = *reinterpret_cast<const uint2*>(p + 4);
    return r.h;
}
__device__ inline half8 ld_h8_g(const _Float16* p) { // global, 16B aligned
    union { half8 h; uint4 u; } r;
    r.u = *reinterpret_cast<const uint4*>(p);
    return r.h;
}
__device__ inline f32x16 zero16() {
    f32x16 z;
#pragma unroll
    for (int i = 0; i < 16; i++) z[i] = 0.f;
    return z;
}
#define MFMA(a, b, c) __builtin_amdgcn_mfma_f32_32x32x16_f16((a), (b), (c), 0, 0, 0)

__global__ __launch_bounds__(256) void gcn_k(
    const float* __restrict__ qs, const float* __restrict__ qf,
    const float* __restrict__ ts, const float* __restrict__ tf,
    const float* __restrict__ ty, const float* __restrict__ Wout,
    const int* __restrict__ nb,
    const _Float16* __restrict__ W0hi, const _Float16* __restrict__ W0lo,
    const _Float16* __restrict__ W1hi, const _Float16* __restrict__ W1lo,
    const _Float16* __restrict__ W2hi, const _Float16* __restrict__ W2lo,
    float* __restrict__ out) {
    __shared__ __align__(16) char Ubuf[36864];   // max(2*32*276*2, 2*256*36*2)
    __shared__ _Float16 Ahhi[32 * PT];
    __shared__ _Float16 Ahlo[32 * PT];
    __shared__ float coords[64];
    __shared__ float dinv[32];
    __shared__ int   idxs[32];

    _Float16* Xhi = (_Float16*)Ubuf;               // [32][PX]
    _Float16* Xlo = (_Float16*)(Ubuf + 17664);     // [32][PX]
    _Float16* Thi = (_Float16*)Ubuf;               // [256][PT]
    _Float16* Tlo = (_Float16*)(Ubuf + 18432);     // [256][PT]

    const int t = threadIdx.x;
    const int w = t >> 6, lane = t & 63;
    const int h = lane >> 5, ln = lane & 31;
    const int q0 = blockIdx.x;

    // ---- indices & coords ----
    if (t < 32) {
        int idx = (t == 0) ? -1 : nb[q0 * KNN + (t - 1)];
        idxs[t] = idx;
        const float* c = (t == 0) ? (qs + (size_t)q0 * 2) : (ts + (size_t)idx * 2);
        coords[t * 2 + 0] = c[0];
        coords[t * 2 + 1] = c[1];
    }
    __syncthreads();

    // ---- build X hi/lo ----
    for (int r = w; r < 32; r += 4) {
        int idx = idxs[r];
        const float* src = (r == 0) ? (qf + (size_t)q0 * 256) : (tf + (size_t)idx * 256);
        float4 v = reinterpret_cast<const float4*>(src)[lane];
        float a4[4] = {v.x, v.y, v.z, v.w};
        _Float16 hi4[4], lo4[4];
#pragma unroll
        for (int j = 0; j < 4; j++) {
            _Float16 hi = (_Float16)a4[j];
            hi4[j] = hi;
            lo4[j] = (_Float16)((a4[j] - (float)hi) * LO_SCALE);
        }
        *reinterpret_cast<uint2*>(&Xhi[r * PX + 4 * lane]) = *reinterpret_cast<uint2*>(hi4);
        *reinterpret_cast<uint2*>(&Xlo[r * PX + 4 * lane]) = *reinterpret_cast<uint2*>(lo4);
        if (lane == 0) {   // K-tail cols 256..271: y, ind, zeros
            float yv = (r == 0) ? 0.f : ty[idx];
            _Float16 thi[16], tlo[16];
#pragma unroll
            for (int j = 0; j < 16; j++) { thi[j] = (_Float16)0.f; tlo[j] = (_Float16)0.f; }
            _Float16 yh = (_Float16)yv;
            thi[0] = yh;
            tlo[0] = (_Float16)((yv - (float)yh) * LO_SCALE);
            thi[1] = (r == 0) ? (_Float16)1.f : (_Float16)0.f;
#pragma unroll
            for (int c = 0; c < 4; c++) {
                *reinterpret_cast<uint2*>(&Xhi[r * PX + 256 + 4 * c]) = reinterpret_cast<uint2*>(thi)[c];
                *reinterpret_cast<uint2*>(&Xlo[r * PX + 256 + 4 * c]) = reinterpret_cast<uint2*>(tlo)[c];
            }
        }
    }

    // ---- Ahat stage 1: row sums -> dinv ----
    if (t < 64) {
        int i = t >> 1, jh = t & 1;
        float xi = coords[i * 2], yi = coords[i * 2 + 1];
        float part = 0.f;
#pragma unroll
        for (int jj = 0; jj < 16; jj++) {
            int j = jh * 16 + jj;
            float dx = xi - coords[j * 2], dy = yi - coords[j * 2 + 1];
            part += __expf(-0.5f * (dx * dx + dy * dy));
        }
        float asum = part + __shfl_xor(part, 1);
        if (jh == 0) dinv[i] = 1.0f / sqrtf(asum);
    }
    __syncthreads();
    // ---- Ahat stage 2: normalize in fp32, split hi/lo ----
    if (t < 64) {
        int i = t >> 1, jh = t & 1;
        float xi = coords[i * 2], yi = coords[i * 2 + 1];
        float di = dinv[i];
        _Float16 ahi[16], alo[16];
#pragma unroll
        for (int jj = 0; jj < 16; jj++) {
            int j = jh * 16 + jj;
            float dx = xi - coords[j * 2], dy = yi - coords[j * 2 + 1];
            float a = __expf(-0.5f * (dx * dx + dy * dy)) * di * dinv[j];
            _Float16 hi = (_Float16)a;
            ahi[jj] = hi;
            alo[jj] = (_Float16)((a - (float)hi) * LO_SCALE);
        }
        _Float16* dh = &Ahhi[i * PT + jh * 16];
        _Float16* dl = &Ahlo[i * PT + jh * 16];
#pragma unroll
        for (int c = 0; c < 4; c++) {
            reinterpret_cast<uint2*>(dh)[c] = reinterpret_cast<uint2*>(ahi)[c];
            reinterpret_cast<uint2*>(dl)[c] = reinterpret_cast<uint2*>(alo)[c];
        }
    }
    __syncthreads();

    // ---- 3 GCN layers ----
    const _Float16* Whis[3] = {W0hi, W1hi, W2hi};
    const _Float16* Wlos[3] = {W0lo, W1lo, W2lo};
    for (int layer = 0; layer < 3; layer++) {
        const _Float16* Whi = Whis[layer];
        const _Float16* Wlo = Wlos[layer];
        const int KS = (layer == 0) ? 17 : 16;

        // GEMM: T = X @ W ; wave w -> feature cols [64w, 64w+64)
        f32x16 acc0 = zero16(), acc1 = zero16();     // hi*hi
        f32x16 cor0 = zero16(), cor1 = zero16();     // lo_s*hi + hi*lo_s
        for (int ks = 0; ks < KS; ks++) {
            half8 Ahi_ = ld_h8(&Xhi[ln * PX + ks * 16 + 8 * h]);
            half8 Alo_ = ld_h8(&Xlo[ln * PX + ks * 16 + 8 * h]);
            const size_t bo = ((size_t)(ks * 8 + 2 * w) * 64 + lane) * 8;
            half8 Bhi0 = ld_h8_g(Whi + bo);
            half8 Bhi1 = ld_h8_g(Whi + bo + 512);
            half8 Blo0 = ld_h8_g(Wlo + bo);
            half8 Blo1 = ld_h8_g(Wlo + bo + 512);
            acc0 = MFMA(Ahi_, Bhi0, acc0);
            cor0 = MFMA(Alo_, Bhi0, cor0);
            cor0 = MFMA(Ahi_, Blo0, cor0);
            acc1 = MFMA(Ahi_, Bhi1, acc1);
            cor1 = MFMA(Alo_, Bhi1, cor1);
            cor1 = MFMA(Ahi_, Blo1, cor1);
        }
        __syncthreads();   // X consumed; Ubuf becomes T^T

        // store T^T hi/lo: D row m=(r&3)+8c+4h is node, col ln is feat-local
#pragma unroll
        for (int a = 0; a < 2; a++) {
            const f32x16& A = a ? acc1 : acc0;
            const f32x16& C = a ? cor1 : cor0;
            int feat = 64 * w + 32 * a + ln;
            _Float16* dh = &Thi[feat * PT + 4 * h];
            _Float16* dl = &Tlo[feat * PT + 4 * h];
#pragma unroll
            for (int c = 0; c < 4; c++) {
                _Float16 vh[4], vl[4];
#pragma unroll
                for (int m = 0; m < 4; m++) {
                    float x = A[4 * c + m] + C[4 * c + m] * LO_INV;
                    _Float16 hi = (_Float16)x;
                    vh[m] = hi;
                    vl[m] = (_Float16)((x - (float)hi) * LO_SCALE);
                }
                *reinterpret_cast<uint2*>(dh + 8 * c) = *reinterpret_cast<uint2*>(vh);
                *reinterpret_cast<uint2*>(dl + 8 * c) = *reinterpret_cast<uint2*>(vl);
            }
        }
        __syncthreads();   // T^T ready

        // apply: OUT^T = T^T * Ahat (Ahat symmetric; row read = col read)
        f32x16 p0 = zero16(), p1 = zero16();
        f32x16 pc0 = zero16(), pc1 = zero16();
#pragma unroll
        for (int ks2 = 0; ks2 < 2; ks2++) {
            half8 bAhi = ld_h8(&Ahhi[ln * PT + ks2 * 16 + 8 * h]);
            half8 bAlo = ld_h8(&Ahlo[ln * PT + ks2 * 16 + 8 * h]);
            half8 t0hi = ld_h8(&Thi[(64 * w + ln) * PT + ks2 * 16 + 8 * h]);
            half8 t0lo = ld_h8(&Tlo[(64 * w + ln) * PT + ks2 * 16 + 8 * h]);
            half8 t1hi = ld_h8(&Thi[(64 * w + 32 + ln) * PT + ks2 * 16 + 8 * h]);
            half8 t1lo = ld_h8(&Tlo[(64 * w + 32 + ln) * PT + ks2 * 16 + 8 * h]);
            p0  = MFMA(t0hi, bAhi, p0);
            pc0 = MFMA(t0lo, bAhi, pc0);
            pc0 = MFMA(t0hi, bAlo, pc0);
            p1  = MFMA(t1hi, bAhi, p1);
            pc1 = MFMA(t1lo, bAhi, pc1);
            pc1 = MFMA(t1hi, bAlo, pc1);
        }
        __syncthreads();   // T^T consumed; Ubuf becomes X/H

        // relu + store H hi/lo (node = ln, feat = 64w + 32a + 8c + 4h + m)
#pragma unroll
        for (int a = 0; a < 2; a++) {
            const f32x16& A = a ? p1 : p0;
            const f32x16& C = a ? pc1 : pc0;
#pragma unroll
            for (int c = 0; c < 4; c++) {
                _Float16 vh[4], vl[4];
#pragma unroll
                for (int m = 0; m < 4; m++) {
                    float x = A[4 * c + m] + C[4 * c + m] * LO_INV;
                    x = x > 0.f ? x : 0.f;
                    _Float16 hi = (_Float16)x;
                    vh[m] = hi;
                    vl[m] = (_Float16)((x - (float)hi) * LO_SCALE);
                }
                int feat = 64 * w + 32 * a + 8 * c + 4 * h;
                *reinterpret_cast<uint2*>(&Xhi[ln * PX + feat]) = *reinterpret_cast<uint2*>(vh);
                *reinterpret_cast<uint2*>(&Xlo[ln * PX + feat]) = *reinterpret_cast<uint2*>(vl);
            }
        }
        __syncthreads();   // H ready
    }

    // ---- head: out = (Hhi + Hlo/1024)[center] . Wout, fp32 ----
    if (w == 0) {
        float4 wv = reinterpret_cast<const float4*>(Wout)[lane];
        union { uint2 u; _Float16 f[4]; } hh, hl;
        hh.u = *reinterpret_cast<const uint2*>(&Xhi[4 * lane]);
        hl.u = *reinterpret_cast<const uint2*>(&Xlo[4 * lane]);
        float s = ((float)hh.f[0] + (float)hl.f[0] * LO_INV) * wv.x
                + ((float)hh.f[1] + (float)hl.f[1] * LO_INV) * wv.y
                + ((float)hh.f[2] + (float)hl.f[2] * LO_INV) * wv.z
                + ((float)hh.f[3] + (float)hl.f[3] * LO_INV) * wv.w;
#pragma unroll
        for (int off = 32; off; off >>= 1) s += __shfl_xor(s, off);
        if (lane == 0) out[q0] = s;
    }
}

// ---------------------------------------------------------------------------
extern "C" void kernel_launch(void* const* d_in, const int* in_sizes, int n_in,
                              void* d_out, int out_size, void* d_ws, size_t ws_size,
                              hipStream_t stream) {
    const float* qs   = (const float*)d_in[0];
    const float* qf   = (const float*)d_in[1];
    const float* ts   = (const float*)d_in[2];
    const float* tf   = (const float*)d_in[3];
    const float* ty   = (const float*)d_in[4];
    const float* W0   = (const float*)d_in[5];
    const float* W1   = (const float*)d_in[6];
    const float* W2   = (const float*)d_in[7];
    const float* Wout = (const float*)d_in[8];
    float* out = (float*)d_out;

    char* ws = (char*)d_ws;
    int*      nb   = (int*)ws;                         // 507,904 B
    _Float16* W0hi = (_Float16*)(ws + 524288);         // 139,264 B
    _Float16* W0lo = (_Float16*)(ws + 663552);         // 139,264 B
    _Float16* W1hi = (_Float16*)(ws + 802816);         // 131,072 B
    _Float16* W1lo = (_Float16*)(ws + 933888);         // 131,072 B
    _Float16* W2hi = (_Float16*)(ws + 1064960);        // 131,072 B
    _Float16* W2lo = (_Float16*)(ws + 1196032);        // 131,072 B

    hipLaunchKernelGGL(prep_weights_k, dim3(98), dim3(256), 0, stream,
                       W0, W1, W2, W0hi, W0lo, W1hi, W1lo, W2hi, W2lo);
    hipLaunchKernelGGL(knn_k, dim3(NQ / QPB), dim3(256), 0, stream, qs, ts, nb);
    hipLaunchKernelGGL(gcn_k, dim3(NQ), dim3(256), 0, stream,
                       qs, qf, ts, tf, ty, Wout, nb,
                       W0hi, W0lo, W1hi, W1lo, W2hi, W2lo, out);
}

// Round 6
// 386.629 us; speedup vs baseline: 2.0226x; 2.0226x over previous
//
#include <hip/hip_runtime.h>

typedef _Float16 half8 __attribute__((ext_vector_type(8)));
typedef float f32x16 __attribute__((ext_vector_type(16)));

#define M_TRAIN 50000
#define NQ 4096
#define KNN 31

#define LO_SCALE 1024.0f
#define LO_INV   9.765625e-4f

// ---------------------------------------------------------------------------
// Weight prep: fp32 -> fp16 hi/lo (lo scaled x1024), B-fragment-major for
// mfma_f32_32x32x16_f16. Wp[ks][nt][lane][j] <- W[ks*16+(lane>>5)*8+j][nt*32+(lane&31)]
// W0: K padded to 272 (rows 256=y, 257=ind, 258..271 = 0). W1/W2: K=256.
// ---------------------------------------------------------------------------
__global__ void prep_weights_k(const float* __restrict__ W0,
                               const float* __restrict__ W1,
                               const float* __restrict__ W2,
                               _Float16* __restrict__ W0hi, _Float16* __restrict__ W0lo,
                               _Float16* __restrict__ W1hi, _Float16* __restrict__ W1lo,
                               _Float16* __restrict__ W2hi, _Float16* __restrict__ W2lo) {
    int t = blockIdx.x * 256 + threadIdx.x;
    const int n0 = 17 * 8 * 64, n1 = 16 * 8 * 64, n2 = 16 * 8 * 64;
    if (t >= n0 + n1 + n2) return;
    const float* src; _Float16 *dhi, *dlo; int idx, Kin;
    if (t < n0)           { src = W0; dhi = W0hi; dlo = W0lo; idx = t;           Kin = 258; }
    else if (t < n0 + n1) { src = W1; dhi = W1hi; dlo = W1lo; idx = t - n0;      Kin = 256; }
    else                  { src = W2; dhi = W2hi; dlo = W2lo; idx = t - n0 - n1; Kin = 256; }
    int lane = idx & 63, nt = (idx >> 6) & 7, ks = idx >> 9;
    int col = nt * 32 + (lane & 31);
    int k0  = ks * 16 + (lane >> 5) * 8;
    _Float16 vhi[8], vlo[8];
#pragma unroll
    for (int j = 0; j < 8; j++) {
        int k = k0 + j;
        float w = (k < Kin) ? src[k * 256 + col] : 0.f;
        _Float16 hi = (_Float16)w;
        vhi[j] = hi;
        vlo[j] = (_Float16)((w - (float)hi) * LO_SCALE);
    }
    *reinterpret_cast<uint4*>(dhi + (size_t)idx * 8) = *reinterpret_cast<const uint4*>(vhi);
    *reinterpret_cast<uint4*>(dlo + (size_t)idx * 8) = *reinterpret_cast<const uint4*>(vlo);
}

// ---------------------------------------------------------------------------
// kNN: exact top-31 under float64 ordering, ties -> lower index.
// One 64-lane wave per query. Pass 1: per-lane top-2 in REGISTERS (no LDS
// atomics, no histogram); 31st-smallest of the 128 merged values is a valid
// upper bound on the true 31st distance (union of per-lane top-2 = 128
// distinct points). Pass 2: collect candidates below bound (+f32/f64 guard).
// Pass 3: exact f64 rank among ~40-60 candidates.
// ---------------------------------------------------------------------------
#define QPB2 4
#define TILE2 2048
#define CAP2 128

__global__ __launch_bounds__(256) void knn_k(const float* __restrict__ qs,
                                             const float* __restrict__ ts,
                                             int* __restrict__ nb) {
    __shared__ __align__(16) float tile[TILE2 * 2];   // 16 KB point staging
    __shared__ float  mrg[QPB2][128];                 // per-wave top-2 merge
    __shared__ int    ci[QPB2][CAP2];                 // candidate indices
    __shared__ double chd[QPB2][CAP2];                // f64 keys
    __shared__ int    cnt[QPB2];

    const int t = threadIdx.x;
    const int w = t >> 6, lane = t & 63;
    const int q = blockIdx.x * QPB2 + w;

    if (lane == 0) cnt[w] = 0;
    const float qx = qs[q * 2 + 0], qy = qs[q * 2 + 1];

    // ---- pass 1: per-lane top-2 scan (registers only) ----
    float v0 = 3.4e38f, v1 = 3.4e38f;
    for (int base = 0; base < M_TRAIN; base += TILE2) {
        const int n = min(TILE2, M_TRAIN - base);
        __syncthreads();
        for (int i = t; i < n / 2; i += 256)
            reinterpret_cast<float4*>(tile)[i] =
                reinterpret_cast<const float4*>(ts + (size_t)base * 2)[i];
        __syncthreads();
#pragma unroll 4
        for (int p = lane; p < n; p += 64) {
            float dx = qx - tile[2 * p], dy = qy - tile[2 * p + 1];
            float d2 = dx * dx + dy * dy;
            if (d2 < v1) { if (d2 < v0) { v1 = v0; v0 = d2; } else v1 = d2; }
        }
    }
    __syncthreads();
    mrg[w][2 * lane]     = v0;
    mrg[w][2 * lane + 1] = v1;
    __syncthreads();

    // ---- 31st smallest of the 128 merged values -> collection threshold ----
    float xa = mrg[w][lane], xb = mrg[w][64 + lane];
    int lea = 0, leb = 0;
    for (int i = 0; i < 128; i++) {
        float v = mrg[w][i];              // broadcast read, conflict-free
        lea += (v <= xa) ? 1 : 0;
        leb += (v <= xb) ? 1 : 0;
    }
    float tc = 3.4e38f;
    if (lea >= 31) tc = xa;
    if (leb >= 31 && xb < tc) tc = xb;
#pragma unroll
    for (int off = 32; off; off >>= 1)
        tc = fminf(tc, __shfl_xor(tc, off));
    const float thr = tc * 1.00001f + 1e-7f;   // covers f32-vs-f64 key noise

    // ---- pass 2: collect candidate indices ----
    for (int base = 0; base < M_TRAIN; base += TILE2) {
        const int n = min(TILE2, M_TRAIN - base);
        __syncthreads();
        for (int i = t; i < n / 2; i += 256)
            reinterpret_cast<float4*>(tile)[i] =
                reinterpret_cast<const float4*>(ts + (size_t)base * 2)[i];
        __syncthreads();
#pragma unroll 4
        for (int p = lane; p < n; p += 64) {
            float dx = qx - tile[2 * p], dy = qy - tile[2 * p + 1];
            float d2 = dx * dx + dy * dy;
            if (d2 < thr) {
                int pos = atomicAdd(&cnt[w], 1);
                if (pos < CAP2) ci[w][pos] = base + p;
            }
        }
    }
    __syncthreads();

    // ---- pass 3: exact float64 rank among candidates, ties -> lower index ----
    const int C = min(cnt[w], CAP2);
    for (int c = lane; c < C; c += 64) {
        int idx = ci[w][c];
        double dx = (double)qx - (double)ts[idx * 2];
        double dy = (double)qy - (double)ts[idx * 2 + 1];
        chd[w][c] = dx * dx + dy * dy;
    }
    __syncthreads();
    for (int c = lane; c < C; c += 64) {
        double key = chd[w][c];
        int   idx = ci[w][c];
        int rank = 0;
        for (int o = 0; o < C; o++) {
            double ok = chd[w][o];
            int    oi = ci[w][o];
            rank += ((ok < key) || (ok == key && oi < idx)) ? 1 : 0;
        }
        if (rank < KNN) nb[q * KNN + rank] = idx;
    }
}

// ---------------------------------------------------------------------------
// Fused graph build + 3-layer GCN + head. 1 graph (32 nodes) per block.
// All fp16 operands carried as (hi, lo*1024); 3-term split MFMA gives
// fp32-accurate products. LDS union: X(hi/lo)[32][276]  <->  T^T(hi/lo)[256][36].
// ---------------------------------------------------------------------------
#define PX 276   // X/H row pitch in fp16
#define PT 36    // T^T / Ahat row pitch in fp16

__device__ inline half8 ld_h8(const _Float16* p) {   // LDS, 8B aligned
    union { half8 h; uint2 u[2]; } r;
    r.u[0] = *reinterpret_cast<const uint2*>(p);
    r.u[1] = *reinterpret_cast<const uint2*>(p + 4);
    return r.h;
}
__device__ inline half8 ld_h8_g(const _Float16* p) { // global, 16B aligned
    union { half8 h; uint4 u; } r;
    r.u = *reinterpret_cast<const uint4*>(p);
    return r.h;
}
__device__ inline f32x16 zero16() {
    f32x16 z;
#pragma unroll
    for (int i = 0; i < 16; i++) z[i] = 0.f;
    return z;
}
#define MFMA(a, b, c) __builtin_amdgcn_mfma_f32_32x32x16_f16((a), (b), (c), 0, 0, 0)

__global__ __launch_bounds__(256) void gcn_k(
    const float* __restrict__ qs, const float* __restrict__ qf,
    const float* __restrict__ ts, const float* __restrict__ tf,
    const float* __restrict__ ty, const float* __restrict__ Wout,
    const int* __restrict__ nb,
    const _Float16* __restrict__ W0hi, const _Float16* __restrict__ W0lo,
    const _Float16* __restrict__ W1hi, const _Float16* __restrict__ W1lo,
    const _Float16* __restrict__ W2hi, const _Float16* __restrict__ W2lo,
    float* __restrict__ out) {
    __shared__ __align__(16) char Ubuf[36864];   // max(2*32*276*2, 2*256*36*2)
    __shared__ _Float16 Ahhi[32 * PT];
    __shared__ _Float16 Ahlo[32 * PT];
    __shared__ float coords[64];
    __shared__ float dinv[32];
    __shared__ int   idxs[32];

    _Float16* Xhi = (_Float16*)Ubuf;               // [32][PX]
    _Float16* Xlo = (_Float16*)(Ubuf + 17664);     // [32][PX]
    _Float16* Thi = (_Float16*)Ubuf;               // [256][PT]
    _Float16* Tlo = (_Float16*)(Ubuf + 18432);     // [256][PT]

    const int t = threadIdx.x;
    const int w = t >> 6, lane = t & 63;
    const int h = lane >> 5, ln = lane & 31;
    const int q0 = blockIdx.x;

    // ---- indices & coords ----
    if (t < 32) {
        int idx = (t == 0) ? -1 : nb[q0 * KNN + (t - 1)];
        idxs[t] = idx;
        const float* c = (t == 0) ? (qs + (size_t)q0 * 2) : (ts + (size_t)idx * 2);
        coords[t * 2 + 0] = c[0];
        coords[t * 2 + 1] = c[1];
    }
    __syncthreads();

    // ---- build X hi/lo ----
    for (int r = w; r < 32; r += 4) {
        int idx = idxs[r];
        const float* src = (r == 0) ? (qf + (size_t)q0 * 256) : (tf + (size_t)idx * 256);
        float4 v = reinterpret_cast<const float4*>(src)[lane];
        float a4[4] = {v.x, v.y, v.z, v.w};
        _Float16 hi4[4], lo4[4];
#pragma unroll
        for (int j = 0; j < 4; j++) {
            _Float16 hi = (_Float16)a4[j];
            hi4[j] = hi;
            lo4[j] = (_Float16)((a4[j] - (float)hi) * LO_SCALE);
        }
        *reinterpret_cast<uint2*>(&Xhi[r * PX + 4 * lane]) = *reinterpret_cast<uint2*>(hi4);
        *reinterpret_cast<uint2*>(&Xlo[r * PX + 4 * lane]) = *reinterpret_cast<uint2*>(lo4);
        if (lane == 0) {   // K-tail cols 256..271: y, ind, zeros
            float yv = (r == 0) ? 0.f : ty[idx];
            _Float16 thi[16], tlo[16];
#pragma unroll
            for (int j = 0; j < 16; j++) { thi[j] = (_Float16)0.f; tlo[j] = (_Float16)0.f; }
            _Float16 yh = (_Float16)yv;
            thi[0] = yh;
            tlo[0] = (_Float16)((yv - (float)yh) * LO_SCALE);
            thi[1] = (r == 0) ? (_Float16)1.f : (_Float16)0.f;
#pragma unroll
            for (int c = 0; c < 4; c++) {
                *reinterpret_cast<uint2*>(&Xhi[r * PX + 256 + 4 * c]) = reinterpret_cast<uint2*>(thi)[c];
                *reinterpret_cast<uint2*>(&Xlo[r * PX + 256 + 4 * c]) = reinterpret_cast<uint2*>(tlo)[c];
            }
        }
    }

    // ---- Ahat stage 1: row sums -> dinv ----
    if (t < 64) {
        int i = t >> 1, jh = t & 1;
        float xi = coords[i * 2], yi = coords[i * 2 + 1];
        float part = 0.f;
#pragma unroll
        for (int jj = 0; jj < 16; jj++) {
            int j = jh * 16 + jj;
            float dx = xi - coords[j * 2], dy = yi - coords[j * 2 + 1];
            part += __expf(-0.5f * (dx * dx + dy * dy));
        }
        float asum = part + __shfl_xor(part, 1);
        if (jh == 0) dinv[i] = 1.0f / sqrtf(asum);
    }
    __syncthreads();
    // ---- Ahat stage 2: normalize in fp32, split hi/lo ----
    if (t < 64) {
        int i = t >> 1, jh = t & 1;
        float xi = coords[i * 2], yi = coords[i * 2 + 1];
        float di = dinv[i];
        _Float16 ahi[16], alo[16];
#pragma unroll
        for (int jj = 0; jj < 16; jj++) {
            int j = jh * 16 + jj;
            float dx = xi - coords[j * 2], dy = yi - coords[j * 2 + 1];
            float a = __expf(-0.5f * (dx * dx + dy * dy)) * di * dinv[j];
            _Float16 hi = (_Float16)a;
            ahi[jj] = hi;
            alo[jj] = (_Float16)((a - (float)hi) * LO_SCALE);
        }
        _Float16* dh = &Ahhi[i * PT + jh * 16];
        _Float16* dl = &Ahlo[i * PT + jh * 16];
#pragma unroll
        for (int c = 0; c < 4; c++) {
            reinterpret_cast<uint2*>(dh)[c] = reinterpret_cast<uint2*>(ahi)[c];
            reinterpret_cast<uint2*>(dl)[c] = reinterpret_cast<uint2*>(alo)[c];
        }
    }
    __syncthreads();

    // ---- 3 GCN layers ----
    const _Float16* Whis[3] = {W0hi, W1hi, W2hi};
    const _Float16* Wlos[3] = {W0lo, W1lo, W2lo};
    for (int layer = 0; layer < 3; layer++) {
        const _Float16* Whi = Whis[layer];
        const _Float16* Wlo = Wlos[layer];
        const int KS = (layer == 0) ? 17 : 16;

        // GEMM: T = X @ W ; wave w -> feature cols [64w, 64w+64)
        f32x16 acc0 = zero16(), acc1 = zero16();     // hi*hi
        f32x16 cor0 = zero16(), cor1 = zero16();     // lo_s*hi + hi*lo_s
        for (int ks = 0; ks < KS; ks++) {
            half8 Ahi_ = ld_h8(&Xhi[ln * PX + ks * 16 + 8 * h]);
            half8 Alo_ = ld_h8(&Xlo[ln * PX + ks * 16 + 8 * h]);
            const size_t bo = ((size_t)(ks * 8 + 2 * w) * 64 + lane) * 8;
            half8 Bhi0 = ld_h8_g(Whi + bo);
            half8 Bhi1 = ld_h8_g(Whi + bo + 512);
            half8 Blo0 = ld_h8_g(Wlo + bo);
            half8 Blo1 = ld_h8_g(Wlo + bo + 512);
            acc0 = MFMA(Ahi_, Bhi0, acc0);
            cor0 = MFMA(Alo_, Bhi0, cor0);
            cor0 = MFMA(Ahi_, Blo0, cor0);
            acc1 = MFMA(Ahi_, Bhi1, acc1);
            cor1 = MFMA(Alo_, Bhi1, cor1);
            cor1 = MFMA(Ahi_, Blo1, cor1);
        }
        __syncthreads();   // X consumed; Ubuf becomes T^T

        // store T^T hi/lo: D row m=(r&3)+8c+4h is node, col ln is feat-local
#pragma unroll
        for (int a = 0; a < 2; a++) {
            const f32x16& A = a ? acc1 : acc0;
            const f32x16& C = a ? cor1 : cor0;
            int feat = 64 * w + 32 * a + ln;
            _Float16* dh = &Thi[feat * PT + 4 * h];
            _Float16* dl = &Tlo[feat * PT + 4 * h];
#pragma unroll
            for (int c = 0; c < 4; c++) {
                _Float16 vh[4], vl[4];
#pragma unroll
                for (int m = 0; m < 4; m++) {
                    float x = A[4 * c + m] + C[4 * c + m] * LO_INV;
                    _Float16 hi = (_Float16)x;
                    vh[m] = hi;
                    vl[m] = (_Float16)((x - (float)hi) * LO_SCALE);
                }
                *reinterpret_cast<uint2*>(dh + 8 * c) = *reinterpret_cast<uint2*>(vh);
                *reinterpret_cast<uint2*>(dl + 8 * c) = *reinterpret_cast<uint2*>(vl);
            }
        }
        __syncthreads();   // T^T ready

        // apply: OUT^T = T^T * Ahat (Ahat symmetric; row read = col read)
        f32x16 p0 = zero16(), p1 = zero16();
        f32x16 pc0 = zero16(), pc1 = zero16();
#pragma unroll
        for (int ks2 = 0; ks2 < 2; ks2++) {
            half8 bAhi = ld_h8(&Ahhi[ln * PT + ks2 * 16 + 8 * h]);
            half8 bAlo = ld_h8(&Ahlo[ln * PT + ks2 * 16 + 8 * h]);
            half8 t0hi = ld_h8(&Thi[(64 * w + ln) * PT + ks2 * 16 + 8 * h]);
            half8 t0lo = ld_h8(&Tlo[(64 * w + ln) * PT + ks2 * 16 + 8 * h]);
            half8 t1hi = ld_h8(&Thi[(64 * w + 32 + ln) * PT + ks2 * 16 + 8 * h]);
            half8 t1lo = ld_h8(&Tlo[(64 * w + 32 + ln) * PT + ks2 * 16 + 8 * h]);
            p0  = MFMA(t0hi, bAhi, p0);
            pc0 = MFMA(t0lo, bAhi, pc0);
            pc0 = MFMA(t0hi, bAlo, pc0);
            p1  = MFMA(t1hi, bAhi, p1);
            pc1 = MFMA(t1lo, bAhi, pc1);
            pc1 = MFMA(t1hi, bAlo, pc1);
        }
        __syncthreads();   // T^T consumed; Ubuf becomes X/H

        // relu + store H hi/lo (node = ln, feat = 64w + 32a + 8c + 4h + m)
#pragma unroll
        for (int a = 0; a < 2; a++) {
            const f32x16& A = a ? p1 : p0;
            const f32x16& C = a ? pc1 : pc0;
#pragma unroll
            for (int c = 0; c < 4; c++) {
                _Float16 vh[4], vl[4];
#pragma unroll
                for (int m = 0; m < 4; m++) {
                    float x = A[4 * c + m] + C[4 * c + m] * LO_INV;
                    x = x > 0.f ? x : 0.f;
                    _Float16 hi = (_Float16)x;
                    vh[m] = hi;
                    vl[m] = (_Float16)((x - (float)hi) * LO_SCALE);
                }
                int feat = 64 * w + 32 * a + 8 * c + 4 * h;
                *reinterpret_cast<uint2*>(&Xhi[ln * PX + feat]) = *reinterpret_cast<uint2*>(vh);
                *reinterpret_cast<uint2*>(&Xlo[ln * PX + feat]) = *reinterpret_cast<uint2*>(vl);
            }
        }
        __syncthreads();   // H ready
    }

    // ---- head: out = (Hhi + Hlo/1024)[center] . Wout, fp32 ----
    if (w == 0) {
        float4 wv = reinterpret_cast<const float4*>(Wout)[lane];
        union { uint2 u; _Float16 f[4]; } hh, hl;
        hh.u = *reinterpret_cast<const uint2*>(&Xhi[4 * lane]);
        hl.u = *reinterpret_cast<const uint2*>(&Xlo[4 * lane]);
        float s = ((float)hh.f[0] + (float)hl.f[0] * LO_INV) * wv.x
                + ((float)hh.f[1] + (float)hl.f[1] * LO_INV) * wv.y
                + ((float)hh.f[2] + (float)hl.f[2] * LO_INV) * wv.z
                + ((float)hh.f[3] + (float)hl.f[3] * LO_INV) * wv.w;
#pragma unroll
        for (int off = 32; off; off >>= 1) s += __shfl_xor(s, off);
        if (lane == 0) out[q0] = s;
    }
}

// ---------------------------------------------------------------------------
extern "C" void kernel_launch(void* const* d_in, const int* in_sizes, int n_in,
                              void* d_out, int out_size, void* d_ws, size_t ws_size,
                              hipStream_t stream) {
    const float* qs   = (const float*)d_in[0];
    const float* qf   = (const float*)d_in[1];
    const float* ts   = (const float*)d_in[2];
    const float* tf   = (const float*)d_in[3];
    const float* ty   = (const float*)d_in[4];
    const float* W0   = (const float*)d_in[5];
    const float* W1   = (const float*)d_in[6];
    const float* W2   = (const float*)d_in[7];
    const float* Wout = (const float*)d_in[8];
    float* out = (float*)d_out;

    char* ws = (char*)d_ws;
    int*      nb   = (int*)ws;                         // 507,904 B
    _Float16* W0hi = (_Float16*)(ws + 524288);         // 139,264 B
    _Float16* W0lo = (_Float16*)(ws + 663552);         // 139,264 B
    _Float16* W1hi = (_Float16*)(ws + 802816);         // 131,072 B
    _Float16* W1lo = (_Float16*)(ws + 933888);         // 131,072 B
    _Float16* W2hi = (_Float16*)(ws + 1064960);        // 131,072 B
    _Float16* W2lo = (_Float16*)(ws + 1196032);        // 131,072 B

    hipLaunchKernelGGL(prep_weights_k, dim3(98), dim3(256), 0, stream,
                       W0, W1, W2, W0hi, W0lo, W1hi, W1lo, W2hi, W2lo);
    hipLaunchKernelGGL(knn_k, dim3(NQ / QPB2), dim3(256), 0, stream, qs, ts, nb);
    hipLaunchKernelGGL(gcn_k, dim3(NQ), dim3(256), 0, stream,
                       qs, qf, ts, tf, ty, Wout, nb,
                       W0hi, W0lo, W1hi, W1lo, W2hi, W2lo, out);
}